// Round 9
// baseline (1242.473 us; speedup 1.0000x reference)
//
#include <hip/hip_runtime.h>

#define BB 64
#define LL 512
#define DD 1024
#define CC 131
#define CP 132
#define START_I 129
#define STOP_I 130
#define NEGV -10000.0f

// Raw workgroup barrier: makes LDS writes visible without draining vmcnt
// (so global stores/prefetches stay in flight across steps).
__device__ __forceinline__ void lds_barrier() {
    asm volatile("s_waitcnt lgkmcnt(0)" ::: "memory");
    __builtin_amdgcn_s_barrier();
    __builtin_amdgcn_sched_barrier(0);
}

// lane-broadcast read of this wave's register (const lane index)
#define RL(src, i) __int_as_float(__builtin_amdgcn_readlane(__float_as_int(src), (i)))

// ---------------- Kernel 1: feats[m][c] = dot(x[m,:], W[c,:]) + b[c] ----------------
#define GM 64
#define GK 32
#define LSTR 36

__global__ __launch_bounds__(256, 2) void gemm_feats(
    const float* __restrict__ x, const float* __restrict__ W,
    const float* __restrict__ bias, float* __restrict__ feats)
{
    __shared__ float xs[GM * LSTR];   // [m][k] 64x36
    __shared__ float ws[CP * LSTR];   // [j][k] 132x36

    const int tid = threadIdx.x;
    const int m0 = blockIdx.x * GM;
    const int tm = tid & 15;          // rows tm + 16r (r<4)
    const int tj = (tid >> 4) & 15;   // cols tj + 16c (c<8)
    const bool tail = (tj < 3);
    const int tjt = (tj < 3) ? tj : 2;

    float acc[4][8];
    float acct[4];
#pragma unroll
    for (int r = 0; r < 4; ++r) {
        acct[r] = 0.f;
#pragma unroll
        for (int c = 0; c < 8; ++c) acc[r][c] = 0.f;
    }

    for (int kc = 0; kc < DD / GK; ++kc) {
        const int k0 = kc * GK;
        if (kc) __syncthreads();
#pragma unroll
        for (int q = 0; q < 2; ++q) {
            int lin = tid + q * 256;
            int m = lin >> 3, c4 = lin & 7;
            float4 v = *(const float4*)&x[(size_t)(m0 + m) * DD + k0 + c4 * 4];
            *(float4*)&xs[m * LSTR + c4 * 4] = v;
        }
#pragma unroll
        for (int q = 0; q < 5; ++q) {
            int lin = tid + q * 256;
            if (lin < CC * 8) {
                int r = lin >> 3, c4 = lin & 7;
                float4 v = *(const float4*)&W[(size_t)r * DD + k0 + c4 * 4];
                *(float4*)&ws[r * LSTR + c4 * 4] = v;
            }
        }
        __syncthreads();

#pragma unroll
        for (int k4 = 0; k4 < 8; ++k4) {
            float4 xr[4], wr[8], wt;
#pragma unroll
            for (int r = 0; r < 4; ++r)
                xr[r] = *(const float4*)&xs[(tm + 16 * r) * LSTR + k4 * 4];
#pragma unroll
            for (int c = 0; c < 8; ++c)
                wr[c] = *(const float4*)&ws[(tj + 16 * c) * LSTR + k4 * 4];
            wt = *(const float4*)&ws[(128 + tjt) * LSTR + k4 * 4];
#pragma unroll
            for (int r = 0; r < 4; ++r) {
#pragma unroll
                for (int c = 0; c < 8; ++c) {
                    acc[r][c] = fmaf(xr[r].x, wr[c].x, acc[r][c]);
                    acc[r][c] = fmaf(xr[r].y, wr[c].y, acc[r][c]);
                    acc[r][c] = fmaf(xr[r].z, wr[c].z, acc[r][c]);
                    acc[r][c] = fmaf(xr[r].w, wr[c].w, acc[r][c]);
                }
                acct[r] = fmaf(xr[r].x, wt.x, acct[r]);
                acct[r] = fmaf(xr[r].y, wt.y, acct[r]);
                acct[r] = fmaf(xr[r].z, wt.z, acct[r]);
                acct[r] = fmaf(xr[r].w, wt.w, acct[r]);
            }
        }
    }

#pragma unroll
    for (int c = 0; c < 8; ++c) {
        int j = tj + 16 * c;
        float bv = bias[j];
#pragma unroll
        for (int r = 0; r < 4; ++r)
            feats[(size_t)(m0 + tm + 16 * r) * CP + j] = acc[r][c] + bv;
    }
    if (tail) {
        int j = 128 + tj;
        float bv = bias[j];
#pragma unroll
        for (int r = 0; r < 4; ++r)
            feats[(size_t)(m0 + tm + 16 * r) * CP + j] = acct[r] + bv;
    }
}

// ---------------- Kernel 2: Viterbi forward v9 ---------------------------------------
// 64 blocks x 320 threads (5 waves). Waves 0..3 = (h = wave>>1, jg = wave&1):
//   lane carries sa = s[h*64+lane]; holds T[j = jg*64+lane][h-half] (64+3 floats, NO
//   keep-alive asm); scans via readlane fan-out from sa (zero LDS in scan); writes one
//   partial to pbuf. Combine for step t happens at START of iter t (software-pipelined)
//   -> ONE lds_barrier per step. Wave 4 owns tail cols 128..130 (3 x 16-lane units,
//   9 T + 9 state floats/lane), publishes tail state via tbuf (3 broadcast scalars).
// All ops exact fp32 add/fmax -> hist bit-identical regardless of order.
__global__ __launch_bounds__(320, 1) void viterbi_fwd(
    const float* __restrict__ feats, const float* __restrict__ mask,
    const float* __restrict__ trans, float* __restrict__ hist)
{
    const int b = blockIdx.x;
    const int tid = threadIdx.x;
    const int wave = tid >> 6, lane = tid & 63;

    __shared__ float pbuf[2][2][132];   // [buf][h][j]
    __shared__ float tbuf[2][4];        // [buf][tail j-128]; tbuf[1] doubles as s_init

    const float* fb = feats + (size_t)b * LL * CP;
    const float* mb = mask + (size_t)b * LL;
    float* hb = hist + (size_t)b * LL * CP;

    if (wave < 4) {
        const int h = wave >> 1;            // i-half
        const int jg = wave & 1;            // j-group
        const int j = jg * 64 + lane;       // scan column
        const int c = h * 64 + lane;        // carried state column
        const bool hstore = (jg == 0);      // waves 0,2 store hist

        // T half-row: 16 float4 (+3 tail scalars when h==1). No keep-alive asm.
        float4 T[16];
        float t16x = NEGV, t16y = NEGV, t16z = NEGV;
        {
            const float* tr = trans + (size_t)j * CC + h * 64;
#pragma unroll
            for (int q = 0; q < 16; ++q) {
                T[q].x = tr[4 * q + 0]; T[q].y = tr[4 * q + 1];
                T[q].z = tr[4 * q + 2]; T[q].w = tr[4 * q + 3];
            }
            if (h == 1) { t16x = tr[64]; t16y = tr[65]; t16z = tr[66]; }  // i=128..130
        }

        if (wave == 0 && lane < 4)
            tbuf[1][lane] = (128 + lane == START_I) ? 0.f : NEGV;   // s_init tails
        lds_barrier();   // bar A

        float sa = NEGV;  // s_init for all carried columns 0..127

#define MAIN_SCAN(TB, WB)                                                       \
        {                                                                       \
            float a0 = -3.0e38f, a1 = -3.0e38f, a2 = -3.0e38f, a3 = -3.0e38f;   \
            _Pragma("unroll")                                                   \
            for (int q = 0; q < 8; ++q) {                                       \
                float4 t4 = T[q];                                               \
                a0 = fmaxf(fmaxf(RL(sa, 4*q+0) + t4.x, RL(sa, 4*q+1) + t4.y), a0); \
                a1 = fmaxf(fmaxf(RL(sa, 4*q+2) + t4.z, RL(sa, 4*q+3) + t4.w), a1); \
            }                                                                   \
            _Pragma("unroll")                                                   \
            for (int q = 8; q < 16; ++q) {                                      \
                float4 t4 = T[q];                                               \
                a2 = fmaxf(fmaxf(RL(sa, 4*q+0) + t4.x, RL(sa, 4*q+1) + t4.y), a2); \
                a3 = fmaxf(fmaxf(RL(sa, 4*q+2) + t4.z, RL(sa, 4*q+3) + t4.w), a3); \
            }                                                                   \
            if (h == 1) {                                                       \
                float u0 = tbuf[TB][0], u1 = tbuf[TB][1], u2 = tbuf[TB][2];     \
                a0 = fmaxf(fmaxf(u0 + t16x, u1 + t16y), a0);                    \
                a1 = fmaxf(a1, u2 + t16z);                                      \
            }                                                                   \
            pbuf[WB][h][j] = fmaxf(fmaxf(a0, a1), fmaxf(a2, a3));               \
        }

        MAIN_SCAN(1, 0)   // prologue: scan s_init -> pbuf[0]
        lds_barrier();    // bar B

        float fv0 = fb[c], fv1 = fb[CP + c];
        float mv0 = mb[0], mv1 = mb[1];
        const float* fb_t = fb + 2 * CP + c;
        const float* mb_t = mb + 2;
        float* hb_t = hb + c;

        for (int t = 0; t < LL; ++t) {
            const int rb = t & 1, wb = rb ^ 1;
            float fv2 = 0.f, mv2 = 1.f;
            if (t + 2 < LL) { fv2 = *fb_t; mv2 = *mb_t; }
            fb_t += CP; ++mb_t;

            // combine (software-pipelined from previous scan)
            float p0 = pbuf[rb][0][c], p1 = pbuf[rb][1][c];
            float ns = (mv0 != 0.f) ? (fmaxf(p0, p1) + fv0) : sa;
            sa = ns;
            if (hstore) *hb_t = ns;
            hb_t += CP;

            if (t < LL - 1) MAIN_SCAN(rb, wb)
            lds_barrier();
            fv0 = fv1; fv1 = fv2; mv0 = mv1; mv1 = mv2;
        }
#undef MAIN_SCAN
    } else {
        // ---- wave 4: tail columns 128..130 ----
        const int g = lane >> 4;                 // 0..3
        const int jt = (g < 3) ? g : 2;          // clamp group 3 (redundant, non-writer)
        const int ch = lane & 15;
        const int i0 = ch * 9;                   // i-range [i0, i0+9)
        const bool wr = (lane < 48) && (ch == 0);
        const int tj = 128 + jt;

        float T9[9], sp[9];
#pragma unroll
        for (int k = 0; k < 9; ++k) {
            int i = i0 + k;
            T9[k] = (i < CC) ? trans[(size_t)tj * CC + i] : NEGV;
            sp[k] = (i == START_I) ? 0.f : NEGV;     // s_init
        }
        lds_barrier();   // bar A

        // prologue: scan s_init -> s_0[tail]
        {
            float m0v = mb[0];
            float f0t = fb[tj];
            float cd = -3.0e38f;
#pragma unroll
            for (int k = 0; k < 9; ++k) cd = fmaxf(cd, sp[k] + T9[k]);
#pragma unroll
            for (int off = 1; off < 16; off <<= 1)
                cd = fmaxf(cd, __shfl_xor(cd, off, 64));
            float st0 = (m0v != 0.f) ? (cd + f0t) : ((tj == START_I) ? 0.f : NEGV);
            if (wr) { tbuf[0][jt] = st0; hb[tj] = st0; }
            sp[0] = sp[0];  // no-op
            // carry tail state in a register on every lane of the group
            // (identical value group-wide; readlane later picks group leaders)
            // store into st below
            asm volatile("" ::: );
            // fallthrough: st initialized after this block
            // (kept simple: assign here)
            // NOTE: st declared below
            // --- handled right after ---
            // (we cannot declare st inside; see below)
            // placeholder
            (void)st0;
            // real assignment after declaration
            // (see st init)
            // --
            // store st0 into shared local via lane-uniform path:
            // we simply re-declare below using the same computation inputs.
            // To avoid recompute, stash in a variable visible below:
            // (moved st declaration above loop instead)
            // -- this comment block intentionally inert --
            __builtin_amdgcn_s_barrier();   // bar B (wave4's copy)
            asm volatile("s_waitcnt lgkmcnt(0)" ::: "memory");
            __builtin_amdgcn_sched_barrier(0);

            float st = st0;
            float f9c[9], f9n[9];
#pragma unroll
            for (int k = 0; k < 9; ++k) {
                int i = i0 + k;
                f9c[k] = fb[(i < 128) ? i : 0];
                f9n[k] = 0.f;
            }
            float ftc = fb[CP + tj];       // f_1[tail]
            float mv0_ = mb[0], mv1_ = mb[1];
            const float* mb_t = mb + 2;
            const float* fpn = fb + CP;    // row t+1 base
            float* ht = hb + CP + tj;      // hist row 1

            for (int t = 0; t < LL; ++t) {
                const int rb = t & 1, wb = rb ^ 1;
                float mv2_ = 1.f, ftn = 0.f;
                if (t + 2 < LL) { mv2_ = *mb_t; ftn = fpn[CP + tj]; }
                ++mb_t;
                if (t + 1 < LL) {
#pragma unroll
                    for (int k = 0; k < 9; ++k) {
                        int i = i0 + k;
                        f9n[k] = fpn[(i < 128) ? i : 0];
                    }
                }
                fpn += CP;

                // combine own 9 state entries
                float rl128 = RL(st, 0), rl129 = RL(st, 16), rl130 = RL(st, 32);
#pragma unroll
                for (int k = 0; k < 9; ++k) {
                    int i = i0 + k;
                    bool lt = (i < 128);
                    int ic = lt ? i : 0;
                    float pm = fmaxf(pbuf[rb][0][ic], pbuf[rb][1][ic]);
                    float cmb = (mv0_ != 0.f) ? (pm + f9c[k]) : sp[k];
                    float tv = (i == 128) ? rl128 :
                               ((i == 129) ? rl129 : ((i == 130) ? rl130 : NEGV));
                    sp[k] = lt ? cmb : tv;
                }

                if (t < LL - 1) {
                    float cd = -3.0e38f;
#pragma unroll
                    for (int k = 0; k < 9; ++k) cd = fmaxf(cd, sp[k] + T9[k]);
#pragma unroll
                    for (int off = 1; off < 16; off <<= 1)
                        cd = fmaxf(cd, __shfl_xor(cd, off, 64));
                    float nst = (mv1_ != 0.f) ? (cd + ftc) : st;
                    st = nst;
                    if (wr) { tbuf[wb][jt] = nst; *ht = nst; }
                }
                ht += CP;
                lds_barrier();
                mv0_ = mv1_; mv1_ = mv2_; ftc = ftn;
#pragma unroll
                for (int k = 0; k < 9; ++k) f9c[k] = f9n[k];
            }
        }
    }
}

// ---------------- Kernel 3: backpointer matrix (unchanged) ----------------
__global__ __launch_bounds__(256, 4) void bp_kernel(
    const float* __restrict__ hist, const float* __restrict__ trans,
    unsigned char* __restrict__ bp)
{
    const int b  = blockIdx.x / 5;
    const int jc = blockIdx.x % 5;
    const int tc = blockIdx.y;
    const int tid = threadIdx.x;
    const int j0 = jc * 32;

    __shared__ float Ts[32][136];
    __shared__ float hs[8][132];

    for (int q = 0; q < 17; ++q) {
        int lin = tid + q * 256;
        if (lin < 32 * CC) {
            int r = lin / CC, i = lin - r * CC;
            if (j0 + r < CC) Ts[r][i] = trans[(size_t)(j0 + r) * CC + i];
        }
    }
    {
        const float4* src = (const float4*)(hist + ((size_t)b * LL + tc * 8) * CP);
#pragma unroll
        for (int q = 0; q < 2; ++q) {
            int lin = tid + q * 256;
            if (lin < (8 * CP) / 4) ((float4*)hs)[lin] = src[lin];
        }
    }
    __syncthreads();

    const int jl = tid & 31;
    const int tt = tid >> 5;
    const int j = j0 + jl;
    const int t = tc * 8 + tt + 1;
    if (j >= CC || t >= LL) return;

    float best; int idx;
    {
        float4 tv = *(const float4*)&Ts[jl][128];
        float4 hv = *(const float4*)&hs[tt][128];
        best = hv.z + tv.z; idx = 130;
        float v;
        v = hv.y + tv.y; if (v >= best) { best = v; idx = 129; }
        v = hv.x + tv.x; if (v >= best) { best = v; idx = 128; }
    }
#pragma unroll
    for (int i4 = 31; i4 >= 0; --i4) {
        float4 tv = *(const float4*)&Ts[jl][i4 * 4];
        float4 hv = *(const float4*)&hs[tt][i4 * 4];
        float v;
        v = hv.w + tv.w; if (v >= best) { best = v; idx = i4 * 4 + 3; }
        v = hv.z + tv.z; if (v >= best) { best = v; idx = i4 * 4 + 2; }
        v = hv.y + tv.y; if (v >= best) { best = v; idx = i4 * 4 + 1; }
        v = hv.x + tv.x; if (v >= best) { best = v; idx = i4 * 4 + 0; }
    }
    bp[((size_t)b * LL + t) * CP + j] = (unsigned char)idx;
}

// ---------------- Kernel 4: final argmax + LDS-streamed u8 backtrack (unchanged) ------
__global__ __launch_bounds__(64, 1) void viterbi_btr(
    const float* __restrict__ hist, const float* __restrict__ trans,
    const unsigned char* __restrict__ bp,
    float* __restrict__ out_score, float* __restrict__ out_path)
{
    const int b = blockIdx.x;
    const int lane = threadIdx.x;
    const float* hb = hist + ((size_t)b * LL + (LL - 1)) * CP;
    const float* ts = trans + (size_t)STOP_I * CC;

    float v0 = hb[lane] + ts[lane];
    float v1 = hb[lane + 64] + ts[lane + 64];
    float v2 = (lane < 3) ? (hb[lane + 128] + ts[lane + 128]) : -3.0e38f;

    float best = v0; int idx = lane;
    if (v1 > best) { best = v1; idx = lane + 64; }
    if (v2 > best) { best = v2; idx = lane + 128; }
#pragma unroll
    for (int off = 32; off >= 1; off >>= 1) {
        float ob = __shfl_xor(best, off, 64);
        int   oi = __shfl_xor(idx, off, 64);
        if (ob > best || (ob == best && oi < idx)) { best = ob; idx = oi; }
    }

    float* op = out_path + (size_t)b * LL;
    if (lane == 0) {
        out_score[b] = best;
        op[LL - 1] = (float)idx;
    }
    int tag = idx;

    __shared__ unsigned char buf[2][1088];
    const unsigned char* bpb = bp + (size_t)b * LL * CP;

    {
        const unsigned int* src = (const unsigned int*)(bpb + (size_t)504 * CP);
        unsigned int* dst = (unsigned int*)buf[1];
#pragma unroll
        for (int q = 0; q < 5; ++q) {
            int lin = lane + q * 64;
            if (lin < 264) dst[lin] = src[lin];
        }
    }
    lds_barrier();

    int cur = 1;
    for (int k = 63; k >= 0; --k) {
        unsigned int r0 = 0, r1 = 0, r2 = 0, r3 = 0, r4 = 0;
        if (k > 0) {
            const unsigned int* src = (const unsigned int*)(bpb + (size_t)(k - 1) * 8 * CP);
            r0 = src[lane];
            r1 = src[lane + 64];
            r2 = src[lane + 128];
            r3 = src[lane + 192];
            if (lane < 8) r4 = src[lane + 256];
        }
        const unsigned char* cb = buf[cur];
#pragma unroll
        for (int s = 7; s >= 0; --s) {
            int t = k * 8 + s;
            if (t >= 1) {
                tag = cb[s * CP + tag];
                if (lane == 0) op[t - 1] = (float)tag;
            }
        }
        if (k > 0) {
            unsigned int* dst = (unsigned int*)buf[cur ^ 1];
            dst[lane] = r0;
            dst[lane + 64] = r1;
            dst[lane + 128] = r2;
            dst[lane + 192] = r3;
            if (lane < 8) dst[lane + 256] = r4;
            lds_barrier();
        }
        cur ^= 1;
    }
}

extern "C" void kernel_launch(void* const* d_in, const int* in_sizes, int n_in,
                              void* d_out, int out_size, void* d_ws, size_t ws_size,
                              hipStream_t stream)
{
    const float* x     = (const float*)d_in[0];
    const float* mask  = (const float*)d_in[1];
    const float* W     = (const float*)d_in[2];
    const float* bias  = (const float*)d_in[3];
    const float* trans = (const float*)d_in[4];

    float* feats = (float*)d_ws;
    float* hist  = feats + (size_t)BB * LL * CP;
    unsigned char* bp = (unsigned char*)(hist + (size_t)BB * LL * CP);
    float* out_score = (float*)d_out;
    float* out_path  = out_score + BB;

    hipLaunchKernelGGL(gemm_feats, dim3((BB * LL) / GM), dim3(256), 0, stream, x, W, bias, feats);
    hipLaunchKernelGGL(viterbi_fwd, dim3(BB), dim3(320), 0, stream, feats, mask, trans, hist);
    hipLaunchKernelGGL(bp_kernel, dim3(BB * 5, 64), dim3(256), 0, stream, hist, trans, bp);
    hipLaunchKernelGGL(viterbi_btr, dim3(BB), dim3(64), 0, stream, hist, trans, bp, out_score, out_path);
}

// Round 10
// 773.488 us; speedup vs baseline: 1.6063x; 1.6063x over previous
//
#include <hip/hip_runtime.h>

#define BB 64
#define LL 512
#define DD 1024
#define CC 131
#define CP 132
#define START_I 129
#define STOP_I 130
#define NEGV -10000.0f

// Raw workgroup barrier: makes LDS writes visible without draining vmcnt
// (so global stores/prefetches stay in flight across steps).
__device__ __forceinline__ void lds_barrier() {
    asm volatile("s_waitcnt lgkmcnt(0)" ::: "memory");
    __builtin_amdgcn_s_barrier();
    __builtin_amdgcn_sched_barrier(0);
}

// ---------------- Kernel 1: feats[m][c] = dot(x[m,:], W[c,:]) + b[c] ----------------
#define GM 64
#define GK 32
#define LSTR 36

__global__ __launch_bounds__(256, 2) void gemm_feats(
    const float* __restrict__ x, const float* __restrict__ W,
    const float* __restrict__ bias, float* __restrict__ feats)
{
    __shared__ float xs[GM * LSTR];   // [m][k] 64x36
    __shared__ float ws[CP * LSTR];   // [j][k] 132x36

    const int tid = threadIdx.x;
    const int m0 = blockIdx.x * GM;
    const int tm = tid & 15;          // rows tm + 16r (r<4)
    const int tj = (tid >> 4) & 15;   // cols tj + 16c (c<8)
    const bool tail = (tj < 3);
    const int tjt = (tj < 3) ? tj : 2;

    float acc[4][8];
    float acct[4];
#pragma unroll
    for (int r = 0; r < 4; ++r) {
        acct[r] = 0.f;
#pragma unroll
        for (int c = 0; c < 8; ++c) acc[r][c] = 0.f;
    }

    for (int kc = 0; kc < DD / GK; ++kc) {
        const int k0 = kc * GK;
        if (kc) __syncthreads();
#pragma unroll
        for (int q = 0; q < 2; ++q) {
            int lin = tid + q * 256;
            int m = lin >> 3, c4 = lin & 7;
            float4 v = *(const float4*)&x[(size_t)(m0 + m) * DD + k0 + c4 * 4];
            *(float4*)&xs[m * LSTR + c4 * 4] = v;
        }
#pragma unroll
        for (int q = 0; q < 5; ++q) {
            int lin = tid + q * 256;
            if (lin < CC * 8) {
                int r = lin >> 3, c4 = lin & 7;
                float4 v = *(const float4*)&W[(size_t)r * DD + k0 + c4 * 4];
                *(float4*)&ws[r * LSTR + c4 * 4] = v;
            }
        }
        __syncthreads();

#pragma unroll
        for (int k4 = 0; k4 < 8; ++k4) {
            float4 xr[4], wr[8], wt;
#pragma unroll
            for (int r = 0; r < 4; ++r)
                xr[r] = *(const float4*)&xs[(tm + 16 * r) * LSTR + k4 * 4];
#pragma unroll
            for (int c = 0; c < 8; ++c)
                wr[c] = *(const float4*)&ws[(tj + 16 * c) * LSTR + k4 * 4];
            wt = *(const float4*)&ws[(128 + tjt) * LSTR + k4 * 4];
#pragma unroll
            for (int r = 0; r < 4; ++r) {
#pragma unroll
                for (int c = 0; c < 8; ++c) {
                    acc[r][c] = fmaf(xr[r].x, wr[c].x, acc[r][c]);
                    acc[r][c] = fmaf(xr[r].y, wr[c].y, acc[r][c]);
                    acc[r][c] = fmaf(xr[r].z, wr[c].z, acc[r][c]);
                    acc[r][c] = fmaf(xr[r].w, wr[c].w, acc[r][c]);
                }
                acct[r] = fmaf(xr[r].x, wt.x, acct[r]);
                acct[r] = fmaf(xr[r].y, wt.y, acct[r]);
                acct[r] = fmaf(xr[r].z, wt.z, acct[r]);
                acct[r] = fmaf(xr[r].w, wt.w, acct[r]);
            }
        }
    }

#pragma unroll
    for (int c = 0; c < 8; ++c) {
        int j = tj + 16 * c;
        float bv = bias[j];
#pragma unroll
        for (int r = 0; r < 4; ++r)
            feats[(size_t)(m0 + tm + 16 * r) * CP + j] = acc[r][c] + bv;
    }
    if (tail) {
        int j = 128 + tj;
        float bv = bias[j];
#pragma unroll
        for (int r = 0; r < 4; ++r)
            feats[(size_t)(m0 + tm + 16 * r) * CP + j] = acct[r] + bv;
    }
}

// ---------------- Kernel 2: Viterbi forward v10 ---------------------------------------
// 64 blocks x 256 threads (4 waves). Wave w: h = w>>1 (i-half), jg = w&1 (j-group).
// Phase A: scan col j = jg*64+lane over i-half h -- T half-row in registers (68 floats,
//   the size class rounds 4/5 proved resident; NO readlane, NO keep-alive asm), s via
//   17 wave-UNIFORM ds_read_b128 (broadcast, conflict-free per r6's 0-conflict result).
//   One pbuf write per lane. [barrier]
// Phase B: w0/w1 combine halves for their col (2 stride-1 pbuf reads + mask-blend),
//   write sbuf[wb] + hist; w2 does tail cols 128..130 (3 x 16-lane groups, 9 stride-9
//   conflict-free reads of the still-intact sbuf[rb], 4 shfl_xor, writers blend+publish);
//   w3 idle. [barrier]
// All candidates are the same single-add fp32 values; fmax in any order is exact ->
// hist bit-identical to the reference recurrence.
__global__ __launch_bounds__(256, 1) void viterbi_fwd(
    const float* __restrict__ feats, const float* __restrict__ mask,
    const float* __restrict__ trans, float* __restrict__ hist)
{
    const int b = blockIdx.x;
    const int tid = threadIdx.x;
    const int w = tid >> 6, lane = tid & 63;
    const int h = w >> 1;              // i-half scanned in phase A
    const int jg = w & 1;
    const int j = jg * 64 + lane;      // scan column (0..127)
    const bool cmb = (h == 0);         // w0,w1 combine in phase B

    __shared__ float sbuf[2][136];     // slot 131 = NEGV pad (never written)
    __shared__ float pbuf[2][2][128];  // [buf][h][j]

    const float* fb = feats + (size_t)b * LL * CP;
    const float* mb = mask + (size_t)b * LL;
    float* hb = hist + (size_t)b * LL * CP;

    // ---- T half-row: 17 float4 = 68 floats (r5's exact load pattern)
    float4 T[17];
    {
        const float* tr = trans + (size_t)j * CC + h * 64;
#pragma unroll
        for (int q = 0; q < 16; ++q) {
            T[q].x = tr[4 * q + 0]; T[q].y = tr[4 * q + 1];
            T[q].z = tr[4 * q + 2]; T[q].w = tr[4 * q + 3];
        }
        if (h == 0) {
            T[16] = make_float4(NEGV, NEGV, NEGV, NEGV);   // pairs s[64..67]; -1e4 never wins
        } else {
            T[16].x = tr[64]; T[16].y = tr[65]; T[16].z = tr[66];  // i = 128..130
            T[16].w = NEGV;                                         // i = 131 pad
        }
    }

    // ---- tail unit data (wave 2 only): 3 cols x 16 lanes x 9 i's
    const int ch = lane & 15;
    const int g0 = lane >> 4;
    const int gt = (g0 < 3) ? g0 : 2;
    const int tj = 128 + gt;
    const bool twr = (w == 2) && (g0 < 3) && (ch == 0);
    float T9[9];
    int ie[9];
    if (w == 2) {
#pragma unroll
        for (int k = 0; k < 9; ++k) {
            int i = ch * 9 + k;
            ie[k] = (i < 132) ? i : 131;                    // clamp into pad slot (NEGV)
            T9[k] = (i < CC) ? trans[(size_t)tj * CC + i] : NEGV;
        }
    }

    // ---- init sbuf (both buffers NEGV, [0][START]=0; slot 131/132..135 stay NEGV)
    for (int q = tid; q < 2 * 136; q += 256) {
        int bi = q / 136, idx = q - bi * 136;
        sbuf[bi][idx] = (bi == 0 && idx == START_I) ? 0.f : NEGV;
    }
    __syncthreads();

    // ---- rings
    float mv0 = mb[0], mv1 = mb[1];
    const float* mb_t = mb + 2;
    float s_prev = NEGV;                       // combiner state (cols 0..127, never START)
    float fv0 = 0.f, fv1 = 0.f;
    const float* fb_t = fb + 2 * CP + j;
    if (cmb) { fv0 = fb[j]; fv1 = fb[CP + j]; }
    float st = (tj == START_I) ? 0.f : NEGV;   // tail state (all w2 lanes of a group agree)
    float ft0 = 0.f, ft1 = 0.f;
    const float* ftb = fb + 2 * CP + tj;
    if (w == 2) { ft0 = fb[tj]; ft1 = fb[CP + tj]; }
    float* hb_j = hb + j;

    for (int t = 0; t < LL; ++t) {
        const int rb = t & 1;

        // ================= phase A: scan (all 4 waves) =================
        {
            const float4* s4 = (const float4*)&sbuf[rb][h * 64];
            float a0 = -3.0e38f, a1 = -3.0e38f, a2 = -3.0e38f, a3 = -3.0e38f;
#pragma unroll
            for (int q = 0; q < 8; ++q) {
                float4 sv = s4[q]; float4 t4 = T[q];
                a0 = fmaxf(fmaxf(sv.x + t4.x, sv.y + t4.y), a0);
                a1 = fmaxf(fmaxf(sv.z + t4.z, sv.w + t4.w), a1);
            }
#pragma unroll
            for (int q = 8; q < 17; ++q) {
                float4 sv = s4[q]; float4 t4 = T[q];
                a2 = fmaxf(fmaxf(sv.x + t4.x, sv.y + t4.y), a2);
                a3 = fmaxf(fmaxf(sv.z + t4.z, sv.w + t4.w), a3);
            }
            pbuf[rb][h][j] = fmaxf(fmaxf(a0, a1), fmaxf(a2, a3));
        }

        lds_barrier();   // pbuf[rb] published; sbuf[rb] reads complete

        // ================= phase B =================
        float fv2 = 0.f, ft2 = 0.f, mv2 = 1.f;
        if (t + 2 < LL) mv2 = *mb_t;
        ++mb_t;

        if (cmb) {
            // combine halves for col j, blend, publish, store hist
            if (t + 2 < LL) fv2 = *fb_t;
            fb_t += CP;
            float p = fmaxf(pbuf[rb][0][j], pbuf[rb][1][j]);
            float ns = (mv0 != 0.f) ? (p + fv0) : s_prev;
            s_prev = ns;
            sbuf[rb ^ 1][j] = ns;
            *hb_j = ns;
        } else if (w == 2) {
            // tail cols 128..130: sbuf[rb] is still intact (overwritten only in
            // phase B of t+1, two barriers away)
            if (t + 2 < LL) ft2 = *ftb;
            ftb += CP;
            float cd = -3.0e38f;
#pragma unroll
            for (int k = 0; k < 9; ++k)
                cd = fmaxf(cd, sbuf[rb][ie[k]] + T9[k]);
#pragma unroll
            for (int off = 1; off < 16; off <<= 1)
                cd = fmaxf(cd, __shfl_xor(cd, off, 64));
            float ns = (mv0 != 0.f) ? (cd + ft0) : st;
            st = ns;
            if (twr) { sbuf[rb ^ 1][tj] = ns; hb[(size_t)t * CP + tj] = ns; }
        }
        hb_j += CP;

        lds_barrier();   // sbuf[rb^1] fully published

        fv0 = fv1; fv1 = fv2; mv0 = mv1; mv1 = mv2; ft0 = ft1; ft1 = ft2;
    }
}

// ---------------- Kernel 3: backpointer matrix (unchanged) ----------------
__global__ __launch_bounds__(256, 4) void bp_kernel(
    const float* __restrict__ hist, const float* __restrict__ trans,
    unsigned char* __restrict__ bp)
{
    const int b  = blockIdx.x / 5;
    const int jc = blockIdx.x % 5;
    const int tc = blockIdx.y;
    const int tid = threadIdx.x;
    const int j0 = jc * 32;

    __shared__ float Ts[32][136];
    __shared__ float hs[8][132];

    for (int q = 0; q < 17; ++q) {
        int lin = tid + q * 256;
        if (lin < 32 * CC) {
            int r = lin / CC, i = lin - r * CC;
            if (j0 + r < CC) Ts[r][i] = trans[(size_t)(j0 + r) * CC + i];
        }
    }
    {
        const float4* src = (const float4*)(hist + ((size_t)b * LL + tc * 8) * CP);
#pragma unroll
        for (int q = 0; q < 2; ++q) {
            int lin = tid + q * 256;
            if (lin < (8 * CP) / 4) ((float4*)hs)[lin] = src[lin];
        }
    }
    __syncthreads();

    const int jl = tid & 31;
    const int tt = tid >> 5;
    const int j = j0 + jl;
    const int t = tc * 8 + tt + 1;
    if (j >= CC || t >= LL) return;

    float best; int idx;
    {
        float4 tv = *(const float4*)&Ts[jl][128];
        float4 hv = *(const float4*)&hs[tt][128];
        best = hv.z + tv.z; idx = 130;
        float v;
        v = hv.y + tv.y; if (v >= best) { best = v; idx = 129; }
        v = hv.x + tv.x; if (v >= best) { best = v; idx = 128; }
    }
#pragma unroll
    for (int i4 = 31; i4 >= 0; --i4) {
        float4 tv = *(const float4*)&Ts[jl][i4 * 4];
        float4 hv = *(const float4*)&hs[tt][i4 * 4];
        float v;
        v = hv.w + tv.w; if (v >= best) { best = v; idx = i4 * 4 + 3; }
        v = hv.z + tv.z; if (v >= best) { best = v; idx = i4 * 4 + 2; }
        v = hv.y + tv.y; if (v >= best) { best = v; idx = i4 * 4 + 1; }
        v = hv.x + tv.x; if (v >= best) { best = v; idx = i4 * 4 + 0; }
    }
    bp[((size_t)b * LL + t) * CP + j] = (unsigned char)idx;
}

// ---------------- Kernel 4: final argmax + LDS-streamed u8 backtrack (unchanged) ------
__global__ __launch_bounds__(64, 1) void viterbi_btr(
    const float* __restrict__ hist, const float* __restrict__ trans,
    const unsigned char* __restrict__ bp,
    float* __restrict__ out_score, float* __restrict__ out_path)
{
    const int b = blockIdx.x;
    const int lane = threadIdx.x;
    const float* hb = hist + ((size_t)b * LL + (LL - 1)) * CP;
    const float* ts = trans + (size_t)STOP_I * CC;

    float v0 = hb[lane] + ts[lane];
    float v1 = hb[lane + 64] + ts[lane + 64];
    float v2 = (lane < 3) ? (hb[lane + 128] + ts[lane + 128]) : -3.0e38f;

    float best = v0; int idx = lane;
    if (v1 > best) { best = v1; idx = lane + 64; }
    if (v2 > best) { best = v2; idx = lane + 128; }
#pragma unroll
    for (int off = 32; off >= 1; off >>= 1) {
        float ob = __shfl_xor(best, off, 64);
        int   oi = __shfl_xor(idx, off, 64);
        if (ob > best || (ob == best && oi < idx)) { best = ob; idx = oi; }
    }

    float* op = out_path + (size_t)b * LL;
    if (lane == 0) {
        out_score[b] = best;
        op[LL - 1] = (float)idx;
    }
    int tag = idx;

    __shared__ unsigned char buf[2][1088];
    const unsigned char* bpb = bp + (size_t)b * LL * CP;

    {
        const unsigned int* src = (const unsigned int*)(bpb + (size_t)504 * CP);
        unsigned int* dst = (unsigned int*)buf[1];
#pragma unroll
        for (int q = 0; q < 5; ++q) {
            int lin = lane + q * 64;
            if (lin < 264) dst[lin] = src[lin];
        }
    }
    lds_barrier();

    int cur = 1;
    for (int k = 63; k >= 0; --k) {
        unsigned int r0 = 0, r1 = 0, r2 = 0, r3 = 0, r4 = 0;
        if (k > 0) {
            const unsigned int* src = (const unsigned int*)(bpb + (size_t)(k - 1) * 8 * CP);
            r0 = src[lane];
            r1 = src[lane + 64];
            r2 = src[lane + 128];
            r3 = src[lane + 192];
            if (lane < 8) r4 = src[lane + 256];
        }
        const unsigned char* cb = buf[cur];
#pragma unroll
        for (int s = 7; s >= 0; --s) {
            int t = k * 8 + s;
            if (t >= 1) {
                tag = cb[s * CP + tag];
                if (lane == 0) op[t - 1] = (float)tag;
            }
        }
        if (k > 0) {
            unsigned int* dst = (unsigned int*)buf[cur ^ 1];
            dst[lane] = r0;
            dst[lane + 64] = r1;
            dst[lane + 128] = r2;
            dst[lane + 192] = r3;
            if (lane < 8) dst[lane + 256] = r4;
            lds_barrier();
        }
        cur ^= 1;
    }
}

extern "C" void kernel_launch(void* const* d_in, const int* in_sizes, int n_in,
                              void* d_out, int out_size, void* d_ws, size_t ws_size,
                              hipStream_t stream)
{
    const float* x     = (const float*)d_in[0];
    const float* mask  = (const float*)d_in[1];
    const float* W     = (const float*)d_in[2];
    const float* bias  = (const float*)d_in[3];
    const float* trans = (const float*)d_in[4];

    float* feats = (float*)d_ws;
    float* hist  = feats + (size_t)BB * LL * CP;
    unsigned char* bp = (unsigned char*)(hist + (size_t)BB * LL * CP);
    float* out_score = (float*)d_out;
    float* out_path  = out_score + BB;

    hipLaunchKernelGGL(gemm_feats, dim3((BB * LL) / GM), dim3(256), 0, stream, x, W, bias, feats);
    hipLaunchKernelGGL(viterbi_fwd, dim3(BB), dim3(256), 0, stream, feats, mask, trans, hist);
    hipLaunchKernelGGL(bp_kernel, dim3(BB * 5, 64), dim3(256), 0, stream, hist, trans, bp);
    hipLaunchKernelGGL(viterbi_btr, dim3(BB), dim3(64), 0, stream, hist, trans, bp, out_score, out_path);
}

// Round 11
// 682.276 us; speedup vs baseline: 1.8211x; 1.1337x over previous
//
#include <hip/hip_runtime.h>

#define BB 64
#define LL 512
#define DD 1024
#define CC 131
#define CP 132
#define START_I 129
#define STOP_I 130
#define NEGV -10000.0f

// Raw workgroup barrier: makes LDS writes visible without draining vmcnt
// (so global stores/prefetches stay in flight across steps).
__device__ __forceinline__ void lds_barrier() {
    asm volatile("s_waitcnt lgkmcnt(0)" ::: "memory");
    __builtin_amdgcn_s_barrier();
    __builtin_amdgcn_sched_barrier(0);
}

// ---------------- Kernel 1: feats[m][c] = dot(x[m,:], W[c,:]) + b[c] ----------------
#define GM 64
#define GK 32
#define LSTR 36

__global__ __launch_bounds__(256, 2) void gemm_feats(
    const float* __restrict__ x, const float* __restrict__ W,
    const float* __restrict__ bias, float* __restrict__ feats)
{
    __shared__ float xs[GM * LSTR];   // [m][k] 64x36
    __shared__ float ws[CP * LSTR];   // [j][k] 132x36

    const int tid = threadIdx.x;
    const int m0 = blockIdx.x * GM;
    const int tm = tid & 15;          // rows tm + 16r (r<4)
    const int tj = (tid >> 4) & 15;   // cols tj + 16c (c<8)
    const bool tail = (tj < 3);
    const int tjt = (tj < 3) ? tj : 2;

    float acc[4][8];
    float acct[4];
#pragma unroll
    for (int r = 0; r < 4; ++r) {
        acct[r] = 0.f;
#pragma unroll
        for (int c = 0; c < 8; ++c) acc[r][c] = 0.f;
    }

    for (int kc = 0; kc < DD / GK; ++kc) {
        const int k0 = kc * GK;
        if (kc) __syncthreads();
#pragma unroll
        for (int q = 0; q < 2; ++q) {
            int lin = tid + q * 256;
            int m = lin >> 3, c4 = lin & 7;
            float4 v = *(const float4*)&x[(size_t)(m0 + m) * DD + k0 + c4 * 4];
            *(float4*)&xs[m * LSTR + c4 * 4] = v;
        }
#pragma unroll
        for (int q = 0; q < 5; ++q) {
            int lin = tid + q * 256;
            if (lin < CC * 8) {
                int r = lin >> 3, c4 = lin & 7;
                float4 v = *(const float4*)&W[(size_t)r * DD + k0 + c4 * 4];
                *(float4*)&ws[r * LSTR + c4 * 4] = v;
            }
        }
        __syncthreads();

#pragma unroll
        for (int k4 = 0; k4 < 8; ++k4) {
            float4 xr[4], wr[8], wt;
#pragma unroll
            for (int r = 0; r < 4; ++r)
                xr[r] = *(const float4*)&xs[(tm + 16 * r) * LSTR + k4 * 4];
#pragma unroll
            for (int c = 0; c < 8; ++c)
                wr[c] = *(const float4*)&ws[(tj + 16 * c) * LSTR + k4 * 4];
            wt = *(const float4*)&ws[(128 + tjt) * LSTR + k4 * 4];
#pragma unroll
            for (int r = 0; r < 4; ++r) {
#pragma unroll
                for (int c = 0; c < 8; ++c) {
                    acc[r][c] = fmaf(xr[r].x, wr[c].x, acc[r][c]);
                    acc[r][c] = fmaf(xr[r].y, wr[c].y, acc[r][c]);
                    acc[r][c] = fmaf(xr[r].z, wr[c].z, acc[r][c]);
                    acc[r][c] = fmaf(xr[r].w, wr[c].w, acc[r][c]);
                }
                acct[r] = fmaf(xr[r].x, wt.x, acct[r]);
                acct[r] = fmaf(xr[r].y, wt.y, acct[r]);
                acct[r] = fmaf(xr[r].z, wt.z, acct[r]);
                acct[r] = fmaf(xr[r].w, wt.w, acct[r]);
            }
        }
    }

#pragma unroll
    for (int c = 0; c < 8; ++c) {
        int j = tj + 16 * c;
        float bv = bias[j];
#pragma unroll
        for (int r = 0; r < 4; ++r)
            feats[(size_t)(m0 + tm + 16 * r) * CP + j] = acc[r][c] + bv;
    }
    if (tail) {
        int j = 128 + tj;
        float bv = bias[j];
#pragma unroll
        for (int r = 0; r < 4; ++r)
            feats[(size_t)(m0 + tm + 16 * r) * CP + j] = acct[r] + bv;
    }
}

// ---------------- Kernel 2: Viterbi forward v11 ---------------------------------------
// 64 blocks x 576 threads (9 waves). i-space padded to 160 (slots 131..159 = NEGV
// forever; pad candidates = -2e4, provably below any real candidate). Thread = (row j,
// sub): waves 0..7 -> j = (w>>2)*64+lane, sub = w&3; wave 8 lanes 0..11 -> tail cols
// 128..130 x 4 subs. Per lane: T[j][sub*40..sub*40+40) = 10 float4 (SMALL -> stays in
// VGPRs; rounds 3-10 showed 64+ float arrays spill). Scan = 10 wave-uniform
// ds_read_b128 (broadcast, conflict-free) + 70 VALU -> 1 pbuf write. Threads 0..130
// combine 4 partials, blend, publish sbuf + hist. Two lgkm barriers/step.
// fmax/add exact in any order -> hist bit-identical to reference.
__global__ __launch_bounds__(576, 1) void viterbi_fwd(
    const float* __restrict__ feats, const float* __restrict__ mask,
    const float* __restrict__ trans, float* __restrict__ hist)
{
    const int b = blockIdx.x;
    const int tid = threadIdx.x;
    const int w = tid >> 6, lane = tid & 63;

    int row, sub;
    bool scw;                     // this thread produces a partial
    if (w < 8) {
        row = (w >> 2) * 64 + lane;   // 0..127
        sub = w & 3;
        scw = true;
    } else {
        int r = 128 + (lane >> 2);
        row = (r <= 130) ? r : 130;   // lanes >=12: clamped duplicate, non-writer
        sub = lane & 3;
        scw = (lane < 12);
    }

    __shared__ float sbuf[2][160];    // [buf][i]; 131..159 = NEGV pad
    __shared__ float pbuf[4][136];    // [sub][j]

    // ---- T slice: 10 float4 = 40 floats, row `row`, i in [sub*40, sub*40+40)
    float4 T[10];
    {
        const float* tr = trans + (size_t)row * CC;
        const int base = sub * 40;
#pragma unroll
        for (int q = 0; q < 10; ++q) {
            float vx = NEGV, vy = NEGV, vz = NEGV, vw = NEGV;
            int i = base + 4 * q;
            if (i + 0 < CC) vx = tr[i + 0];
            if (i + 1 < CC) vy = tr[i + 1];
            if (i + 2 < CC) vz = tr[i + 2];
            if (i + 3 < CC) vw = tr[i + 3];
            T[q].x = vx; T[q].y = vy; T[q].z = vz; T[q].w = vw;
        }
    }

    // ---- init sbuf: all NEGV, [0][START]=0. pbuf needs no init (cols 0..130 are
    // all written each step before being read; cols 131..135 never read).
    for (int q = tid; q < 2 * 160; q += 576) {
        int bi = q / 160, idx = q - bi * 160;
        sbuf[bi][idx] = (bi == 0 && idx == START_I) ? 0.f : NEGV;
    }
    __syncthreads();

    const float* fb = feats + (size_t)b * LL * CP;
    const float* mb = mask + (size_t)b * LL;
    float* hb = hist + (size_t)b * LL * CP;

    // ---- combiner state (threads 0..130 own column k)
    const int k = tid;
    const bool cmb = (tid < 131);
    float s_prev = (k == START_I) ? 0.f : NEGV;
    float fv0 = 0.f, fv1 = 0.f, mv0 = 1.f, mv1 = 1.f;
    const float* fb_t = fb + 2 * CP + k;
    const float* mb_t = mb + 2;
    float* hb_k = hb + k;
    if (cmb) { fv0 = fb[k]; fv1 = fb[CP + k]; mv0 = mb[0]; mv1 = mb[1]; }

    for (int t = 0; t < LL; ++t) {
        const int rb = t & 1;

        // ================= phase A: scan (all 9 waves) =================
        {
            const float4* s4 = (const float4*)sbuf[rb] + sub * 10;
            float a0 = -3.0e38f, a1 = -3.0e38f, a2 = -3.0e38f, a3 = -3.0e38f;
#pragma unroll
            for (int q = 0; q < 5; ++q) {
                float4 sv = s4[q]; float4 t4 = T[q];
                a0 = fmaxf(fmaxf(sv.x + t4.x, sv.y + t4.y), a0);
                a1 = fmaxf(fmaxf(sv.z + t4.z, sv.w + t4.w), a1);
            }
#pragma unroll
            for (int q = 5; q < 10; ++q) {
                float4 sv = s4[q]; float4 t4 = T[q];
                a2 = fmaxf(fmaxf(sv.x + t4.x, sv.y + t4.y), a2);
                a3 = fmaxf(fmaxf(sv.z + t4.z, sv.w + t4.w), a3);
            }
            if (scw) pbuf[sub][row] = fmaxf(fmaxf(a0, a1), fmaxf(a2, a3));
        }

        lds_barrier();   // pbuf published; sbuf[rb] reads complete

        // ================= phase B: combine (threads 0..130) =================
        if (cmb) {
            float fv2 = 0.f, mv2 = 1.f;
            if (t + 2 < LL) { fv2 = *fb_t; mv2 = *mb_t; }
            fb_t += CP; ++mb_t;

            float p = fmaxf(fmaxf(pbuf[0][k], pbuf[1][k]),
                            fmaxf(pbuf[2][k], pbuf[3][k]));
            float ns = (mv0 != 0.f) ? (p + fv0) : s_prev;
            s_prev = ns;
            sbuf[rb ^ 1][k] = ns;
            *hb_k = ns;                       // global store, never drained by barrier
            hb_k += CP;

            fv0 = fv1; fv1 = fv2; mv0 = mv1; mv1 = mv2;
        }

        lds_barrier();   // sbuf[rb^1] fully published
    }
}

// ---------------- Kernel 3: backpointer matrix (unchanged) ----------------
__global__ __launch_bounds__(256, 4) void bp_kernel(
    const float* __restrict__ hist, const float* __restrict__ trans,
    unsigned char* __restrict__ bp)
{
    const int b  = blockIdx.x / 5;
    const int jc = blockIdx.x % 5;
    const int tc = blockIdx.y;
    const int tid = threadIdx.x;
    const int j0 = jc * 32;

    __shared__ float Ts[32][136];
    __shared__ float hs[8][132];

    for (int q = 0; q < 17; ++q) {
        int lin = tid + q * 256;
        if (lin < 32 * CC) {
            int r = lin / CC, i = lin - r * CC;
            if (j0 + r < CC) Ts[r][i] = trans[(size_t)(j0 + r) * CC + i];
        }
    }
    {
        const float4* src = (const float4*)(hist + ((size_t)b * LL + tc * 8) * CP);
#pragma unroll
        for (int q = 0; q < 2; ++q) {
            int lin = tid + q * 256;
            if (lin < (8 * CP) / 4) ((float4*)hs)[lin] = src[lin];
        }
    }
    __syncthreads();

    const int jl = tid & 31;
    const int tt = tid >> 5;
    const int j = j0 + jl;
    const int t = tc * 8 + tt + 1;
    if (j >= CC || t >= LL) return;

    float best; int idx;
    {
        float4 tv = *(const float4*)&Ts[jl][128];
        float4 hv = *(const float4*)&hs[tt][128];
        best = hv.z + tv.z; idx = 130;
        float v;
        v = hv.y + tv.y; if (v >= best) { best = v; idx = 129; }
        v = hv.x + tv.x; if (v >= best) { best = v; idx = 128; }
    }
#pragma unroll
    for (int i4 = 31; i4 >= 0; --i4) {
        float4 tv = *(const float4*)&Ts[jl][i4 * 4];
        float4 hv = *(const float4*)&hs[tt][i4 * 4];
        float v;
        v = hv.w + tv.w; if (v >= best) { best = v; idx = i4 * 4 + 3; }
        v = hv.z + tv.z; if (v >= best) { best = v; idx = i4 * 4 + 2; }
        v = hv.y + tv.y; if (v >= best) { best = v; idx = i4 * 4 + 1; }
        v = hv.x + tv.x; if (v >= best) { best = v; idx = i4 * 4 + 0; }
    }
    bp[((size_t)b * LL + t) * CP + j] = (unsigned char)idx;
}

// ---------------- Kernel 4: final argmax + LDS-streamed u8 backtrack (unchanged) ------
__global__ __launch_bounds__(64, 1) void viterbi_btr(
    const float* __restrict__ hist, const float* __restrict__ trans,
    const unsigned char* __restrict__ bp,
    float* __restrict__ out_score, float* __restrict__ out_path)
{
    const int b = blockIdx.x;
    const int lane = threadIdx.x;
    const float* hb = hist + ((size_t)b * LL + (LL - 1)) * CP;
    const float* ts = trans + (size_t)STOP_I * CC;

    float v0 = hb[lane] + ts[lane];
    float v1 = hb[lane + 64] + ts[lane + 64];
    float v2 = (lane < 3) ? (hb[lane + 128] + ts[lane + 128]) : -3.0e38f;

    float best = v0; int idx = lane;
    if (v1 > best) { best = v1; idx = lane + 64; }
    if (v2 > best) { best = v2; idx = lane + 128; }
#pragma unroll
    for (int off = 32; off >= 1; off >>= 1) {
        float ob = __shfl_xor(best, off, 64);
        int   oi = __shfl_xor(idx, off, 64);
        if (ob > best || (ob == best && oi < idx)) { best = ob; idx = oi; }
    }

    float* op = out_path + (size_t)b * LL;
    if (lane == 0) {
        out_score[b] = best;
        op[LL - 1] = (float)idx;
    }
    int tag = idx;

    __shared__ unsigned char buf[2][1088];
    const unsigned char* bpb = bp + (size_t)b * LL * CP;

    {
        const unsigned int* src = (const unsigned int*)(bpb + (size_t)504 * CP);
        unsigned int* dst = (unsigned int*)buf[1];
#pragma unroll
        for (int q = 0; q < 5; ++q) {
            int lin = lane + q * 64;
            if (lin < 264) dst[lin] = src[lin];
        }
    }
    lds_barrier();

    int cur = 1;
    for (int k = 63; k >= 0; --k) {
        unsigned int r0 = 0, r1 = 0, r2 = 0, r3 = 0, r4 = 0;
        if (k > 0) {
            const unsigned int* src = (const unsigned int*)(bpb + (size_t)(k - 1) * 8 * CP);
            r0 = src[lane];
            r1 = src[lane + 64];
            r2 = src[lane + 128];
            r3 = src[lane + 192];
            if (lane < 8) r4 = src[lane + 256];
        }
        const unsigned char* cb = buf[cur];
#pragma unroll
        for (int s = 7; s >= 0; --s) {
            int t = k * 8 + s;
            if (t >= 1) {
                tag = cb[s * CP + tag];
                if (lane == 0) op[t - 1] = (float)tag;
            }
        }
        if (k > 0) {
            unsigned int* dst = (unsigned int*)buf[cur ^ 1];
            dst[lane] = r0;
            dst[lane + 64] = r1;
            dst[lane + 128] = r2;
            dst[lane + 192] = r3;
            if (lane < 8) dst[lane + 256] = r4;
            lds_barrier();
        }
        cur ^= 1;
    }
}

extern "C" void kernel_launch(void* const* d_in, const int* in_sizes, int n_in,
                              void* d_out, int out_size, void* d_ws, size_t ws_size,
                              hipStream_t stream)
{
    const float* x     = (const float*)d_in[0];
    const float* mask  = (const float*)d_in[1];
    const float* W     = (const float*)d_in[2];
    const float* bias  = (const float*)d_in[3];
    const float* trans = (const float*)d_in[4];

    float* feats = (float*)d_ws;
    float* hist  = feats + (size_t)BB * LL * CP;
    unsigned char* bp = (unsigned char*)(hist + (size_t)BB * LL * CP);
    float* out_score = (float*)d_out;
    float* out_path  = out_score + BB;

    hipLaunchKernelGGL(gemm_feats, dim3((BB * LL) / GM), dim3(256), 0, stream, x, W, bias, feats);
    hipLaunchKernelGGL(viterbi_fwd, dim3(BB), dim3(576), 0, stream, feats, mask, trans, hist);
    hipLaunchKernelGGL(bp_kernel, dim3(BB * 5, 64), dim3(256), 0, stream, hist, trans, bp);
    hipLaunchKernelGGL(viterbi_btr, dim3(BB), dim3(64), 0, stream, hist, trans, bp, out_score, out_path);
}